// Round 2
// baseline (330.139 us; speedup 1.0000x reference)
//
#include <hip/hip_runtime.h>

// x: [B,H,S,16] fp32, rows = B*H*S = 262144
// out per row: [1, x*0.5, (x_i*x_j)*inv_s2rd] -> 273 floats
// 4 rows per block -> 1092 floats = 273 float4 (16B aligned per chunk)

#define FDIM 16
#define OUT_PER_ROW 273
#define ROWS_PER_BLOCK 4
#define CHUNK_FLOATS (ROWS_PER_BLOCK * OUT_PER_ROW)   // 1092
#define CHUNK_VEC4 (CHUNK_FLOATS / 4)                 // 273

__global__ __launch_bounds__(256) void based_feature_kernel(
    const float* __restrict__ x, float* __restrict__ out, int nchunks)
{
    constexpr float INV_RRD  = 0.5f;                    // 1/sqrt(sqrt(16)) = 1/2
    constexpr float INV_S2RD = 0.17677669529663687f;    // 1/(sqrt(2)*4)

    __shared__ float xs[ROWS_PER_BLOCK * FDIM];         // 64 floats

    const int chunk = blockIdx.x;
    if (chunk >= nchunks) return;
    const int t = threadIdx.x;

    // stage 4 rows of x (64 floats) into LDS: threads 0..15 load one float4 each
    if (t < (ROWS_PER_BLOCK * FDIM) / 4) {
        const float4* x4 = reinterpret_cast<const float4*>(x) +
                           (size_t)chunk * (ROWS_PER_BLOCK * FDIM / 4);
        float4 v = x4[t];
        xs[4 * t + 0] = v.x;
        xs[4 * t + 1] = v.y;
        xs[4 * t + 2] = v.z;
        xs[4 * t + 3] = v.w;
    }
    __syncthreads();

    float4* out4 = reinterpret_cast<float4*>(out) + (size_t)chunk * CHUNK_VEC4;

#pragma unroll
    for (int pass = 0; pass < 2; ++pass) {
        const int q = t + pass * 256;
        if (q < CHUNK_VEC4) {
            float4 v;
            float* vp = &v.x;
            const int f0 = q * 4;
#pragma unroll
            for (int e = 0; e < 4; ++e) {
                const int f  = f0 + e;
                const int rl = f / OUT_PER_ROW;         // 0..3, magic-mul
                const int k  = f - rl * OUT_PER_ROW;    // 0..272
                const float* xr = &xs[rl * FDIM];
                float val;
                if (k == 0) {
                    val = 1.0f;
                } else if (k <= FDIM) {
                    val = xr[k - 1] * INV_RRD;
                } else {
                    const int kk = k - (FDIM + 1);
                    val = xr[kk >> 4] * xr[kk & 15] * INV_S2RD;
                }
                vp[e] = val;
            }
            out4[q] = v;
        }
    }
}

extern "C" void kernel_launch(void* const* d_in, const int* in_sizes, int n_in,
                              void* d_out, int out_size, void* d_ws, size_t ws_size,
                              hipStream_t stream) {
    const float* x = (const float*)d_in[0];
    float* out = (float*)d_out;

    const int total_x = in_sizes[0];           // B*H*S*16
    const int nrows   = total_x / FDIM;        // 262144
    const int nchunks = nrows / ROWS_PER_BLOCK; // 65536 (nrows divisible by 4)

    based_feature_kernel<<<dim3(nchunks), dim3(256), 0, stream>>>(x, out, nchunks);
}

// Round 4
// 297.682 us; speedup vs baseline: 1.1090x; 1.1090x over previous
//
#include <hip/hip_runtime.h>

// x: [B,H,S,16] fp32, rows = 262144
// out per row: [1, x*0.5, (x_i*x_j)*0.176776695] -> 273 floats (fp32)
// Block = 256 threads handles 64 rows: 64*273 = 17472 floats = 4368 float4,
// contiguous + 16B-aligned. x staged in LDS (4 KB).

#define FDIM 16
#define OUT_PER_ROW 273
#define ROWS_PER_BLOCK 64
#define SUPER_FLOATS (ROWS_PER_BLOCK * OUT_PER_ROW)   // 17472
#define SUPER_VEC4   (SUPER_FLOATS / 4)               // 4368 = 17*256 + 16
#define X_FLOATS     (ROWS_PER_BLOCK * FDIM)          // 1024
#define X_VEC4       (X_FLOATS / 4)                   // 256

typedef float fvec4 __attribute__((ext_vector_type(4)));

__global__ __launch_bounds__(256) void based_feature_kernel(
    const float* __restrict__ x, float* __restrict__ out)
{
    constexpr float INV_RRD  = 0.5f;                  // 1/sqrt(sqrt(16))
    constexpr float INV_S2RD = 0.17677669529663687f;  // 1/(sqrt(2)*4)

    __shared__ float xs[X_FLOATS];

    const int t  = threadIdx.x;
    const int sc = blockIdx.x;

    // stage 64 rows of x (4 KB) — every thread loads one float4
    {
        const fvec4* x4 = reinterpret_cast<const fvec4*>(x) + (size_t)sc * X_VEC4;
        reinterpret_cast<fvec4*>(xs)[t] = x4[t];
    }
    __syncthreads();

    fvec4* out4 = reinterpret_cast<fvec4*>(out) + (size_t)sc * SUPER_VEC4;

#pragma unroll 2
    for (int p = 0; p < 18; ++p) {
        const int q = p * 256 + t;
        if (q < SUPER_VEC4) {
            const int f0 = q * 4;
            fvec4 v;
#pragma unroll
            for (int e = 0; e < 4; ++e) {
                const int f = f0 + e;
                const int r = f / OUT_PER_ROW;        // 0..63 (magic-mul)
                const int k = f - r * OUT_PER_ROW;    // 0..272
                const float* xr = &xs[r * FDIM];
                float val;
                if (k == 0) {
                    val = 1.0f;
                } else if (k <= FDIM) {
                    val = xr[k - 1] * INV_RRD;
                } else {
                    const int kk = k - (FDIM + 1);
                    val = xr[kk >> 4] * xr[kk & 15] * INV_S2RD;
                }
                v[e] = val;
            }
            __builtin_nontemporal_store(v, &out4[q]);
        }
    }
}

extern "C" void kernel_launch(void* const* d_in, const int* in_sizes, int n_in,
                              void* d_out, int out_size, void* d_ws, size_t ws_size,
                              hipStream_t stream) {
    const float* x = (const float*)d_in[0];
    float* out = (float*)d_out;

    const int total_x = in_sizes[0];                  // B*H*S*16
    const int nrows   = total_x / FDIM;               // 262144
    const int nsuper  = nrows / ROWS_PER_BLOCK;       // 4096

    based_feature_kernel<<<dim3(nsuper), dim3(256), 0, stream>>>(x, out);
}